// Round 1
// baseline (359.447 us; speedup 1.0000x reference)
//
#include <hip/hip_runtime.h>

typedef unsigned short u16;
typedef unsigned int   u32;
typedef __attribute__((ext_vector_type(8))) short bf16x8;
typedef __attribute__((ext_vector_type(4))) float f32x4;

#define SCALE 0.17677669529663687f  // 32^-0.5

__device__ __forceinline__ u16 f2bf(float f){
  u32 x = __float_as_uint(f);
  x += 0x7fffu + ((x >> 16) & 1u);   // RNE
  return (u16)(x >> 16);
}
__device__ __forceinline__ float bf2f(u16 u){
  return __uint_as_float(((u32)u) << 16);
}

// ---- ws layout (bytes) ----
// 0        : qkvw_bf16   [1536][512]            1,572,864
// 1572864  : projw_bf16  [512][512]               524,288
// 2097152  : biasT bf16  [16][64][64]             131,072
// 2228224  : scaleT bf16 [16][64][64]             131,072
// 2359296  : qkv ws bf16 [1024][16][3][64][32]  201,326,592
// 203685888: x_bf16 [65536][512] (later reused as attn_out) 67,108,864
// total: 270,794,752

// ---------------- prep: weights->bf16, expand rel tables ----------------
__global__ void prep_kernel(const float* __restrict__ qkvw, const float* __restrict__ projw,
                            const float* __restrict__ table, const int* __restrict__ relidx,
                            u16* __restrict__ qkvw_b, u16* __restrict__ projw_b,
                            u16* __restrict__ biasT, u16* __restrict__ scaleT){
  int i = blockIdx.x * 256 + threadIdx.x;
  if (i < 786432) {
    qkvw_b[i] = f2bf(qkvw[i]);
  } else if (i < 1048576) {
    int j = i - 786432; projw_b[j] = f2bf(projw[j]);
  } else if (i < 1114112) {
    int j = i - 1048576; int h = j >> 12, rc = j & 4095;
    int idx = relidx[rc];
    biasT [h*4096 + rc] = f2bf(table[idx*32 + h]);
    scaleT[h*4096 + rc] = f2bf(table[idx*32 + 16 + h]);
  }
}

// ---------------- x (fp32) -> bf16 ----------------
__global__ void xconv_kernel(const float* __restrict__ x, u16* __restrict__ xb){
  size_t i = (size_t)blockIdx.x * 256 + threadIdx.x;  // one thread per 8 elems
  const float4* xp = (const float4*)x;
  float4 a = xp[2*i], b = xp[2*i+1];
  union { u16 u[8]; uint4 v; } o;
  o.u[0]=f2bf(a.x); o.u[1]=f2bf(a.y); o.u[2]=f2bf(a.z); o.u[3]=f2bf(a.w);
  o.u[4]=f2bf(b.x); o.u[5]=f2bf(b.y); o.u[6]=f2bf(b.z); o.u[7]=f2bf(b.w);
  *(uint4*)(xb + 8*i) = o.v;
}

// ---------------- GEMM: C[M][NC] = A_bf16[M][512] @ W_bf16[NC][512]^T ----------------
// EPI 0: qkv epilogue (bias add, q*=SCALE, scatter bf16 to qkv ws)
// EPI 1: proj epilogue (bias add, fp32 store to d_out)
template<int EPI>
__global__ __launch_bounds__(256) void gemm_kernel(
    const u16* __restrict__ A, const u16* __restrict__ W,
    const float* __restrict__ bias, void* __restrict__ outp, int ntiles)
{
  __shared__ u16 As[2][4096];   // [128 rows][32 k]
  __shared__ u16 Bs[2][4096];   // [128 cols][32 k]
  const int tid = threadIdx.x, lane = tid & 63, wid = tid >> 6;
  const int mt = blockIdx.x / ntiles, nt = blockIdx.x % ntiles;
  const size_t m0 = (size_t)mt * 128;
  const int n0 = nt * 128;
  const int wm = wid >> 1, wn = wid & 1;

  const f32x4 z = {0.f, 0.f, 0.f, 0.f};
  f32x4 acc[4][4];
#pragma unroll
  for (int i = 0; i < 4; i++)
#pragma unroll
    for (int j = 0; j < 4; j++) acc[i][j] = z;

  auto stage = [&](int buf, int kt){
    const int k0 = kt << 5;
#pragma unroll
    for (int c = 0; c < 2; c++){
      const int u = wid*128 + c*64 + lane;
      const int row = u >> 2, un = u & 3;
      const u16* ga = A + (m0 + row)*512 + k0 + un*8;
      const u16* gb = W + (size_t)(n0 + row)*512 + k0 + un*8;
      u16* la = &As[buf][(wid*128 + c*64)*8];   // wave-uniform LDS base
      u16* lb = &Bs[buf][(wid*128 + c*64)*8];
      __builtin_amdgcn_global_load_lds((const __attribute__((address_space(1))) u32*)ga,
                                       (__attribute__((address_space(3))) u32*)la, 16, 0, 0);
      __builtin_amdgcn_global_load_lds((const __attribute__((address_space(1))) u32*)gb,
                                       (__attribute__((address_space(3))) u32*)lb, 16, 0, 0);
    }
  };

  stage(0, 0);
  __syncthreads();
#pragma unroll 2
  for (int kt = 0; kt < 16; ++kt){
    const int buf = kt & 1;
    if (kt < 15) stage(buf ^ 1, kt + 1);
    bf16x8 af[4], bfr[4];
#pragma unroll
    for (int i = 0; i < 4; i++){
      af[i]  = *(const bf16x8*)&As[buf][(wm*64 + i*16 + (lane&15))*32 + ((lane>>4)<<3)];
      bfr[i] = *(const bf16x8*)&Bs[buf][(wn*64 + i*16 + (lane&15))*32 + ((lane>>4)<<3)];
    }
#pragma unroll
    for (int i = 0; i < 4; i++)
#pragma unroll
      for (int j = 0; j < 4; j++)
        acc[i][j] = __builtin_amdgcn_mfma_f32_16x16x32_bf16(af[i], bfr[j], acc[i][j], 0, 0, 0);
    __syncthreads();
  }

  const int lr = (lane >> 4) << 2;
  const int lc = lane & 15;
  if (EPI == 0){
    u16* q = (u16*)outp;
#pragma unroll
    for (int j = 0; j < 4; j++){
      const int c = n0 + wn*64 + j*16 + lc;
      const float bv = bias[c];
      const int which = c >> 9, h = (c >> 5) & 15, d = c & 31;
      const size_t cbase = (size_t)which*2048 + d;
#pragma unroll
      for (int i = 0; i < 4; i++){
#pragma unroll
        for (int r = 0; r < 4; r++){
          const size_t row = m0 + wm*64 + i*16 + lr + r;
          const int b = (int)(row >> 6), n = (int)(row & 63);
          float v = acc[i][j][r] + bv;
          if (which == 0) v *= SCALE;
          q[(size_t)(b*16 + h)*6144 + cbase + n*32] = f2bf(v);
        }
      }
    }
  } else {
    float* o = (float*)outp;
#pragma unroll
    for (int j = 0; j < 4; j++){
      const int c = n0 + wn*64 + j*16 + lc;
      const float bv = bias[c];
#pragma unroll
      for (int i = 0; i < 4; i++){
#pragma unroll
        for (int r = 0; r < 4; r++){
          const size_t row = m0 + wm*64 + i*16 + lr + r;
          o[row*512 + c] = acc[i][j][r] + bv;
        }
      }
    }
  }
}

// ---------------- attention: one block per (b,h) ----------------
__global__ __launch_bounds__(256) void attn_kernel(
    const u16* __restrict__ qkv, const u16* __restrict__ biasT,
    const u16* __restrict__ scaleT, u16* __restrict__ attn_out)
{
  __shared__ u16 qs[64*40];   // [64][32] pad->40 elems (80B rows, conflict-free b128 reads)
  __shared__ u16 ks[64*40];
  __shared__ u16 vs[64*40];
  __shared__ u16 Ps[64*72];   // [64][64] pad->72 (144B rows)
  const int tid = threadIdx.x, lane = tid & 63, wid = tid >> 6;
  const int bh = blockIdx.x, b = bh >> 4, h = bh & 15;
  const u16* base = qkv + (size_t)bh * 6144;
  {
    const int row = tid >> 2, un = (tid & 3) * 8;
    *(uint4*)&qs[row*40 + un] = *(const uint4*)(base + row*32 + un);
    *(uint4*)&ks[row*40 + un] = *(const uint4*)(base + 2048 + row*32 + un);
    *(uint4*)&vs[row*40 + un] = *(const uint4*)(base + 4096 + row*32 + un);
  }
  __syncthreads();

  const int wr0 = wid * 16;
  const int lg = lane >> 4, lc = lane & 15;
  const f32x4 z = {0.f, 0.f, 0.f, 0.f};

  // S = q @ k^T  (q pre-scaled in GEMM epilogue); A-frag rows = wave's 16 rows
  bf16x8 qf = *(const bf16x8*)&qs[(wr0 + lc)*40 + lg*8];
  f32x4 s[4];
#pragma unroll
  for (int ct = 0; ct < 4; ++ct){
    bf16x8 kf = *(const bf16x8*)&ks[(ct*16 + lc)*40 + lg*8];
    s[ct] = __builtin_amdgcn_mfma_f32_16x16x32_bf16(qf, kf, z, 0, 0, 0);
  }

  const u16* bT = biasT + h*4096;
  const u16* sT = scaleT + h*4096;
#pragma unroll
  for (int r = 0; r < 4; ++r){
    const int row = wr0 + lg*4 + r;
    float vals[4]; float mx = -1e30f;
#pragma unroll
    for (int ct = 0; ct < 4; ++ct){
      vals[ct] = s[ct][r] + bf2f(bT[row*64 + ct*16 + lc]);
      mx = fmaxf(mx, vals[ct]);
    }
    mx = fmaxf(mx, __shfl_xor(mx, 1));
    mx = fmaxf(mx, __shfl_xor(mx, 2));
    mx = fmaxf(mx, __shfl_xor(mx, 4));
    mx = fmaxf(mx, __shfl_xor(mx, 8));
    float sm = 0.f;
#pragma unroll
    for (int ct = 0; ct < 4; ++ct){ vals[ct] = __expf(vals[ct] - mx); sm += vals[ct]; }
    sm += __shfl_xor(sm, 1);
    sm += __shfl_xor(sm, 2);
    sm += __shfl_xor(sm, 4);
    sm += __shfl_xor(sm, 8);
    const float inv = 1.f / sm;
#pragma unroll
    for (int ct = 0; ct < 4; ++ct){
      const int col = ct*16 + lc;
      Ps[row*72 + col] = f2bf(vals[ct] * inv * bf2f(sT[row*64 + col]));
    }
  }
  __syncthreads();

  // out = P @ V : A-frag from Ps (own rows), B-frag from vs (scalar gathers, 2-way free)
  f32x4 o[2] = {z, z};
#pragma unroll
  for (int kc = 0; kc < 2; ++kc){
    bf16x8 pf = *(const bf16x8*)&Ps[(wr0 + lc)*72 + kc*32 + lg*8];
#pragma unroll
    for (int c2 = 0; c2 < 2; ++c2){
      union { u16 u[8]; bf16x8 v; } vf;
#pragma unroll
      for (int e = 0; e < 8; ++e)
        vf.u[e] = vs[(kc*32 + lg*8 + e)*40 + c2*16 + lc];
      o[c2] = __builtin_amdgcn_mfma_f32_16x16x32_bf16(pf, vf.v, o[c2], 0, 0, 0);
    }
  }

#pragma unroll
  for (int c2 = 0; c2 < 2; ++c2){
#pragma unroll
    for (int r = 0; r < 4; ++r){
      const int n = wr0 + lg*4 + r;
      attn_out[((size_t)b*64 + n)*512 + h*32 + c2*16 + lc] = f2bf(o[c2][r]);
    }
  }
}

extern "C" void kernel_launch(void* const* d_in, const int* in_sizes, int n_in,
                              void* d_out, int out_size, void* d_ws, size_t ws_size,
                              hipStream_t stream)
{
  const float* x      = (const float*)d_in[0];
  const float* qkvw   = (const float*)d_in[1];
  const float* qkvb   = (const float*)d_in[2];
  const float* projw  = (const float*)d_in[3];
  const float* projb  = (const float*)d_in[4];
  const float* table  = (const float*)d_in[5];
  const int*   relidx = (const int*)d_in[6];
  char* ws = (char*)d_ws;

  u16* qkvw_b = (u16*)(ws + 0);
  u16* projw_b= (u16*)(ws + 1572864);
  u16* biasT  = (u16*)(ws + 2097152);
  u16* scaleT = (u16*)(ws + 2228224);
  u16* qkvws  = (u16*)(ws + 2359296);
  u16* xb     = (u16*)(ws + 203685888);  // reused as attn_out after qkv GEMM
  u16* attn_o = xb;

  if (ws_size < 270794752ull) return;  // ws too small — fail loudly via validation

  prep_kernel<<<dim3(4352), dim3(256), 0, stream>>>(qkvw, projw, table, relidx,
                                                    qkvw_b, projw_b, biasT, scaleT);
  xconv_kernel<<<dim3(16384), dim3(256), 0, stream>>>(x, xb);
  gemm_kernel<0><<<dim3(6144), dim3(256), 0, stream>>>(xb, qkvw_b, qkvb, (void*)qkvws, 12);
  attn_kernel<<<dim3(16384), dim3(256), 0, stream>>>(qkvws, biasT, scaleT, attn_o);
  gemm_kernel<1><<<dim3(2048), dim3(256), 0, stream>>>(attn_o, projw_b, projb, d_out, 4);
}

// Round 2
// 301.999 us; speedup vs baseline: 1.1902x; 1.1902x over previous
//
#include <hip/hip_runtime.h>

typedef unsigned short u16;
typedef unsigned int   u32;
typedef __attribute__((ext_vector_type(8))) short bf16x8;
typedef __attribute__((ext_vector_type(4))) float f32x4;

#define SCALE 0.17677669529663687f  // 32^-0.5

__device__ __forceinline__ u16 f2bf(float f){
  u32 x = __float_as_uint(f);
  x += 0x7fffu + ((x >> 16) & 1u);   // RNE
  return (u16)(x >> 16);
}
__device__ __forceinline__ float bf2f(u16 u){
  return __uint_as_float(((u32)u) << 16);
}

// ---- ws layout (bytes) ----
// 0        : qkvw_bf16   [1536][512]            1,572,864
// 1572864  : projw_bf16  [512][512]               524,288
// 2097152  : biasT bf16  [16][64][64]             131,072
// 2228224  : scaleT bf16 [16][64][64]             131,072
// 2359296  : qkv bf16 [65536][1536] coalesced   201,326,592
// 203685888: x_bf16 [65536][512] (later reused as attn_out) 67,108,864

// ---------------- prep: weights->bf16, expand rel tables ----------------
__global__ void prep_kernel(const float* __restrict__ qkvw, const float* __restrict__ projw,
                            const float* __restrict__ table, const int* __restrict__ relidx,
                            u16* __restrict__ qkvw_b, u16* __restrict__ projw_b,
                            u16* __restrict__ biasT, u16* __restrict__ scaleT){
  int i = blockIdx.x * 256 + threadIdx.x;
  if (i < 786432) {
    qkvw_b[i] = f2bf(qkvw[i]);
  } else if (i < 1048576) {
    int j = i - 786432; projw_b[j] = f2bf(projw[j]);
  } else if (i < 1114112) {
    int j = i - 1048576; int h = j >> 12, rc = j & 4095;
    int idx = relidx[rc];
    biasT [h*4096 + rc] = f2bf(table[idx*32 + h]);
    scaleT[h*4096 + rc] = f2bf(table[idx*32 + 16 + h]);
  }
}

// ---------------- x (fp32) -> bf16 ----------------
__global__ void xconv_kernel(const float* __restrict__ x, u16* __restrict__ xb){
  size_t i = (size_t)blockIdx.x * 256 + threadIdx.x;  // one thread per 8 elems
  const float4* xp = (const float4*)x;
  float4 a = xp[2*i], b = xp[2*i+1];
  union { u16 u[8]; uint4 v; } o;
  o.u[0]=f2bf(a.x); o.u[1]=f2bf(a.y); o.u[2]=f2bf(a.z); o.u[3]=f2bf(a.w);
  o.u[4]=f2bf(b.x); o.u[5]=f2bf(b.y); o.u[6]=f2bf(b.z); o.u[7]=f2bf(b.w);
  *(uint4*)(xb + 8*i) = o.v;
}

// ============ GEMM: C[M][NC] = A_bf16[M][512] @ W_bf16[NC][512]^T ============
// BM=128, BN=256, BK=64, 8 waves (2Mx4N), ring-3 LDS, counted vmcnt(6), T2 swizzle.
// EPI 0: qkv epilogue (bias, q*=SCALE, bf16 store to [M][1536])
// EPI 1: proj epilogue (bias, fp32 store to [M][512])
template<int EPI>
__global__ __launch_bounds__(512, 2) void gemm_kernel(
    const u16* __restrict__ A, const u16* __restrict__ W,
    const float* __restrict__ bias, void* __restrict__ outp, const int NT)
{
  // slot: A [128 rows][64 k] @ u16 0..8191 ; B [256 cols][64 k] @ 8192..24575
  // physical 16B-slot p of row r holds logical k-slot (p ^ (r&7))
  __shared__ u16 lds[3][24576];   // 3 x 48KB = 144KB
  const int tid = threadIdx.x, lane = tid & 63, wid = tid >> 6;
  const int wave_base = tid & ~63;

  // bijective XCD swizzle (gridDim.x % 8 == 0 for both uses)
  const int cpx = gridDim.x >> 3;
  const int bid = (blockIdx.x & 7) * cpx + (blockIdx.x >> 3);
  const int mt = bid / NT, nt = bid % NT;
  const size_t m0 = (size_t)mt * 128;
  const int n0 = nt * 256;
  const int wm = wid >> 2, wn = wid & 3;
  const int NCOL = (EPI == 0) ? 1536 : 512;

  const f32x4 z = {0.f, 0.f, 0.f, 0.f};
  f32x4 acc[4][4];
#pragma unroll
  for (int i = 0; i < 4; i++)
#pragma unroll
    for (int j = 0; j < 4; j++) acc[i][j] = z;

  // stage chunk ch (K-bytes [ch*128, ch*128+128)) into slot ch%3
  auto stage = [&](int ch){
    const int slot = ch % 3;
    const int kb = ch * 128;
    u16* base = &lds[slot][0];
    // A: 2 calls of 8KB
#pragma unroll
    for (int c = 0; c < 2; ++c){
      const int t = c*512 + tid;
      const int row = t >> 3, sl = t & 7;
      const char* ga = (const char*)A + (m0 + row)*1024 + kb + ((sl ^ (row & 7)) << 4);
      u16* la = base + (size_t)(c*512 + wave_base)*8;
      __builtin_amdgcn_global_load_lds((const __attribute__((address_space(1))) u32*)ga,
                                       (__attribute__((address_space(3))) u32*)la, 16, 0, 0);
    }
    // B: 4 calls of 8KB
#pragma unroll
    for (int c = 0; c < 4; ++c){
      const int t = c*512 + tid;
      const int col = t >> 3, sl = t & 7;
      const char* gb = (const char*)W + (size_t)(n0 + col)*1024 + kb + ((sl ^ (col & 7)) << 4);
      u16* lb = base + 8192 + (size_t)(c*512 + wave_base)*8;
      __builtin_amdgcn_global_load_lds((const __attribute__((address_space(1))) u32*)gb,
                                       (__attribute__((address_space(3))) u32*)lb, 16, 0, 0);
    }
  };

  auto compute = [&](int ch){
    const int slot = ch % 3;
    const u16* As = &lds[slot][0];
    const u16* Bs = &lds[slot][8192];
    bf16x8 af[2][4], bfr[2][4];
#pragma unroll
    for (int kk = 0; kk < 2; ++kk){
#pragma unroll
      for (int i = 0; i < 4; ++i){
        const int row = wm*64 + i*16 + (lane & 15);
        const int sa  = (kk*4 + (lane >> 4)) ^ (row & 7);
        af[kk][i] = *(const bf16x8*)&As[row*64 + sa*8];
        const int col = wn*64 + i*16 + (lane & 15);
        const int sb  = (kk*4 + (lane >> 4)) ^ (col & 7);
        bfr[kk][i] = *(const bf16x8*)&Bs[col*64 + sb*8];
      }
    }
    asm volatile("s_waitcnt lgkmcnt(0)" ::: "memory");
    __builtin_amdgcn_sched_barrier(0);
    __builtin_amdgcn_s_setprio(1);
#pragma unroll
    for (int kk = 0; kk < 2; ++kk)
#pragma unroll
      for (int i = 0; i < 4; ++i)
#pragma unroll
        for (int j = 0; j < 4; ++j)
          acc[i][j] = __builtin_amdgcn_mfma_f32_16x16x32_bf16(af[kk][i], bfr[kk][j], acc[i][j], 0, 0, 0);
    __builtin_amdgcn_s_setprio(0);
  };

  // prologue: chunks 0,1 in flight; wait chunk 0 (oldest 6), keep chunk 1 flying
  stage(0);
  stage(1);
  asm volatile("s_waitcnt vmcnt(6)" ::: "memory");
  __builtin_amdgcn_s_barrier();

#pragma unroll
  for (int ch = 0; ch < 8; ++ch){
    if (ch + 2 < 8) stage(ch + 2);
    compute(ch);
    if (ch < 7){
      if (ch + 2 < 8) { asm volatile("s_waitcnt vmcnt(6)" ::: "memory"); }
      else            { asm volatile("s_waitcnt vmcnt(0)" ::: "memory"); }
      __builtin_amdgcn_s_barrier();
    }
  }

  // epilogue (coalesced linear stores)
  const int lr = (lane >> 4) << 2;
  const int lc = lane & 15;
  if (EPI == 0){
    u16* o = (u16*)outp;
#pragma unroll
    for (int j = 0; j < 4; ++j){
      const int col = n0 + wn*64 + j*16 + lc;
      const float bv = bias[col];
      const float sc = (col < 512) ? SCALE : 1.f;
#pragma unroll
      for (int i = 0; i < 4; ++i){
#pragma unroll
        for (int r = 0; r < 4; ++r){
          const size_t row = m0 + wm*64 + i*16 + lr + r;
          o[row*1536 + col] = f2bf((acc[i][j][r] + bv) * sc);
        }
      }
    }
  } else {
    float* o = (float*)outp;
#pragma unroll
    for (int j = 0; j < 4; ++j){
      const int col = n0 + wn*64 + j*16 + lc;
      const float bv = bias[col];
#pragma unroll
      for (int i = 0; i < 4; ++i){
#pragma unroll
        for (int r = 0; r < 4; ++r){
          const size_t row = m0 + wm*64 + i*16 + lr + r;
          o[row*512 + col] = acc[i][j][r] + bv;
        }
      }
    }
  }
}

// ---------------- attention: one block per (b,h), qkv in [M][1536] ----------------
__global__ __launch_bounds__(256) void attn_kernel(
    const u16* __restrict__ qkv, const u16* __restrict__ biasT,
    const u16* __restrict__ scaleT, u16* __restrict__ attn_out)
{
  __shared__ u16 qs[64*40];   // [64][32] pad->40 elems
  __shared__ u16 ks[64*40];
  __shared__ u16 vs[64*40];
  __shared__ u16 Ps[64*72];   // [64][64] pad->72
  const int tid = threadIdx.x, lane = tid & 63, wid = tid >> 6;
  const int bh = blockIdx.x, b = bh >> 4, h = bh & 15;
  const u16* base = qkv + (size_t)b * 64 * 1536 + h * 32;
  {
    const int row = tid >> 2, seg = (tid & 3) * 8;
    const size_t ro = (size_t)row * 1536 + seg;
    *(uint4*)&qs[row*40 + seg] = *(const uint4*)(base + ro);
    *(uint4*)&ks[row*40 + seg] = *(const uint4*)(base + ro + 512);
    *(uint4*)&vs[row*40 + seg] = *(const uint4*)(base + ro + 1024);
  }
  __syncthreads();

  const int wr0 = wid * 16;
  const int lg = lane >> 4, lc = lane & 15;
  const f32x4 z = {0.f, 0.f, 0.f, 0.f};

  // S = q @ k^T  (q pre-scaled in GEMM epilogue)
  bf16x8 qf = *(const bf16x8*)&qs[(wr0 + lc)*40 + lg*8];
  f32x4 s[4];
#pragma unroll
  for (int ct = 0; ct < 4; ++ct){
    bf16x8 kf = *(const bf16x8*)&ks[(ct*16 + lc)*40 + lg*8];
    s[ct] = __builtin_amdgcn_mfma_f32_16x16x32_bf16(qf, kf, z, 0, 0, 0);
  }

  const u16* bT = biasT + h*4096;
  const u16* sT = scaleT + h*4096;
#pragma unroll
  for (int r = 0; r < 4; ++r){
    const int row = wr0 + lg*4 + r;
    float vals[4]; float mx = -1e30f;
#pragma unroll
    for (int ct = 0; ct < 4; ++ct){
      vals[ct] = s[ct][r] + bf2f(bT[row*64 + ct*16 + lc]);
      mx = fmaxf(mx, vals[ct]);
    }
    mx = fmaxf(mx, __shfl_xor(mx, 1));
    mx = fmaxf(mx, __shfl_xor(mx, 2));
    mx = fmaxf(mx, __shfl_xor(mx, 4));
    mx = fmaxf(mx, __shfl_xor(mx, 8));
    float sm = 0.f;
#pragma unroll
    for (int ct = 0; ct < 4; ++ct){ vals[ct] = __expf(vals[ct] - mx); sm += vals[ct]; }
    sm += __shfl_xor(sm, 1);
    sm += __shfl_xor(sm, 2);
    sm += __shfl_xor(sm, 4);
    sm += __shfl_xor(sm, 8);
    const float inv = 1.f / sm;
#pragma unroll
    for (int ct = 0; ct < 4; ++ct){
      const int col = ct*16 + lc;
      Ps[row*72 + col] = f2bf(vals[ct] * inv * bf2f(sT[row*64 + col]));
    }
  }
  __syncthreads();

  // out = P @ V
  f32x4 o[2] = {z, z};
#pragma unroll
  for (int kc = 0; kc < 2; ++kc){
    bf16x8 pf = *(const bf16x8*)&Ps[(wr0 + lc)*72 + kc*32 + lg*8];
#pragma unroll
    for (int c2 = 0; c2 < 2; ++c2){
      union { u16 u[8]; bf16x8 v; } vf;
#pragma unroll
      for (int e = 0; e < 8; ++e)
        vf.u[e] = vs[(kc*32 + lg*8 + e)*40 + c2*16 + lc];
      o[c2] = __builtin_amdgcn_mfma_f32_16x16x32_bf16(pf, vf.v, o[c2], 0, 0, 0);
    }
  }

#pragma unroll
  for (int c2 = 0; c2 < 2; ++c2){
#pragma unroll
    for (int r = 0; r < 4; ++r){
      const int n = wr0 + lg*4 + r;
      attn_out[((size_t)b*64 + n)*512 + h*32 + c2*16 + lc] = f2bf(o[c2][r]);
    }
  }
}

extern "C" void kernel_launch(void* const* d_in, const int* in_sizes, int n_in,
                              void* d_out, int out_size, void* d_ws, size_t ws_size,
                              hipStream_t stream)
{
  const float* x      = (const float*)d_in[0];
  const float* qkvw   = (const float*)d_in[1];
  const float* qkvb   = (const float*)d_in[2];
  const float* projw  = (const float*)d_in[3];
  const float* projb  = (const float*)d_in[4];
  const float* table  = (const float*)d_in[5];
  const int*   relidx = (const int*)d_in[6];
  char* ws = (char*)d_ws;

  u16* qkvw_b = (u16*)(ws + 0);
  u16* projw_b= (u16*)(ws + 1572864);
  u16* biasT  = (u16*)(ws + 2097152);
  u16* scaleT = (u16*)(ws + 2228224);
  u16* qkvws  = (u16*)(ws + 2359296);      // [65536][1536] bf16
  u16* xb     = (u16*)(ws + 203685888);    // reused as attn_out after qkv GEMM
  u16* attn_o = xb;

  if (ws_size < 270794752ull) return;

  prep_kernel<<<dim3(4352), dim3(256), 0, stream>>>(qkvw, projw, table, relidx,
                                                    qkvw_b, projw_b, biasT, scaleT);
  xconv_kernel<<<dim3(16384), dim3(256), 0, stream>>>(x, xb);
  gemm_kernel<0><<<dim3(3072), dim3(512), 0, stream>>>(xb, qkvw_b, qkvb, (void*)qkvws, 6);
  attn_kernel<<<dim3(16384), dim3(256), 0, stream>>>(qkvws, biasT, scaleT, attn_o);
  gemm_kernel<1><<<dim3(1024), dim3(512), 0, stream>>>(attn_o, projw_b, projb, d_out, 2);
}